// Round 8
// baseline (507.784 us; speedup 1.0000x reference)
//
#include <hip/hip_runtime.h>
#include <hip/hip_bf16.h>

#define NN 100000
#define EE 1600000
#define GG 32
#define INC 100
#define HC 64
#define CAP 64        // ELL row capacity; P(Poisson(16) > 64) ~ 2e-18 per node
#define BN_EPS 1e-5f
#define NB_POOL 1563  // ceil(NN/64)
#define WQ 32767.0f   // 15-bit quantization scale
#define NSLICE 8      // XCD slices
#define SLICE_N 12500 // nodes per slice
#define NGEMM 3125    // gemm-role blocks in merged kernel (NN/32)
#define NSCAT 50000   // scatter-role blocks (EE/256 * NSLICE)

typedef __hip_bfloat16 bf16;

__device__ __forceinline__ float bflo(unsigned u) { return __uint_as_float(u << 16); }
__device__ __forceinline__ float bfhi(unsigned u) { return __uint_as_float(u & 0xffff0000u); }
__device__ __forceinline__ unsigned f2bf(float f) {
    unsigned x = __float_as_uint(f);
    return (x + 0x7fffu + ((x >> 16) & 1u)) >> 16;
}
__device__ __forceinline__ unsigned bfpack(float lo, float hi) {
    return f2bf(lo) | (f2bf(hi) << 16);
}

// -------- MERGED: layer-0 GEMM (blocks 0..NGEMM-1)  ||  XCD-sliced ELL scatter --------
// Scatter is TCC/latency-bound (VALUBusy 8%, 1.8/6.3 TB/s) -> CUs have slack; the
// data-independent gemm0 rides in the same dispatch on its own blocks.
// Scatter role: Round-2 config exactly (1 edge/thread, NT reads; R3: ILP regressed).
// Slice invariant preserved: slice = b&7 (== XCD of block b), chunk = (b-NGEMM)>>3;
// for each chunk the 8 consecutive b cover all 8 slices bijectively.
// Gemm role: Ws-only LDS (25.6 KB -> 6 blocks/CU = 24 waves = scatter's measured 75%);
// x rows read via L1-broadcast loads. Writes RAW fp32 h0raw (no dinv dependency);
// k_dinv_scale applies dinv with the same single bf16 rounding as before.

__global__ __launch_bounds__(256) void k_scatter_gemm0(
    const int* __restrict__ ei, const float* __restrict__ ew,
    int* __restrict__ cur, unsigned* __restrict__ epk,
    const float* __restrict__ x, const float* __restrict__ W0,
    float* __restrict__ h0raw) {
    __shared__ float Ws[INC * 64];
    unsigned b = blockIdx.x;
    if (b < NGEMM) {
        int row0 = (int)b * 32;
        for (int idx = threadIdx.x; idx < INC * 64; idx += 256)
            Ws[idx] = W0[idx];
        __syncthreads();
        int c = threadIdx.x & 63;
        int r0 = threadIdx.x >> 6;   // 0..3
        float acc[8];
#pragma unroll
        for (int j = 0; j < 8; j++) acc[j] = 0.f;
        const float* xb = x + (size_t)row0 * INC;
        for (int k = 0; k < INC; k++) {
            float wv = Ws[k * 64 + c];
#pragma unroll
            for (int j = 0; j < 8; j++)
                acc[j] += xb[(size_t)(r0 + j * 4) * INC + k] * wv;
        }
#pragma unroll
        for (int j = 0; j < 8; j++)
            h0raw[(size_t)(row0 + r0 + j * 4) * 64 + c] = acc[j];
        return;
    }
    unsigned bb = b - NGEMM;
    int slice = b & (NSLICE - 1);        // == XCD of block b (round-robin)
    int e = (int)(bb >> 3) * 256 + threadIdx.x;
    if (e >= EE) return;
    int d = __builtin_nontemporal_load(&ei[EE + e]);
    int lo = slice * SLICE_N;
    if (d < lo || d >= lo + SLICE_N) return;
    int s = __builtin_nontemporal_load(&ei[e]);
    float w = __builtin_nontemporal_load(&ew[e]);
    int qw = (int)(fabsf(w) * WQ + 0.5f);
    if (qw > 32767) qw = 32767;
    int slot = atomicAdd(&cur[d], 1);
    if (slot < CAP)
        epk[(size_t)d * CAP + slot] = ((unsigned)s << 15) | (unsigned)qw;
}

// wave per node: lane-sum of dequantized |w| -> dinv; then scale the node's raw
// fp32 gemm0 row by dinv and pack to bf16 (single rounding, same as old epilogue).
// Block 0 also zeroes the pooling accumulators (replaces 2 memset dispatches).

__global__ __launch_bounds__(256) void k_dinv_scale(
    const int* __restrict__ cur, const unsigned* __restrict__ epk,
    float* __restrict__ dinv, const float* __restrict__ h0raw,
    unsigned* __restrict__ hw32out,
    float* __restrict__ pool_s, float* __restrict__ pool_c) {
    if (blockIdx.x == 0) {
        for (int i = threadIdx.x; i < GG * 64 + GG; i += 256) {
            if (i < GG * 64) pool_s[i] = 0.f;
            else             pool_c[i - GG * 64] = 0.f;
        }
    }
    int wid = (blockIdx.x * 256 + threadIdx.x) >> 6;
    int lane = threadIdx.x & 63;
    if (wid >= NN) return;
    int cnt = min(cur[wid], CAP);
    float v = 0.f;
    if (lane < cnt)
        v = (float)(epk[(size_t)wid * CAP + lane] & 0x7fffu) * (1.0f / WQ);
    for (int o = 32; o > 0; o >>= 1) v += __shfl_down(v, o);
    v = __shfl(v, 0);                       // broadcast sum
    float di = rsqrtf(v + 1.0f);            // +1 = self-loop weight
    if (lane == 0) dinv[wid] = di;
    if (lane < 32) {
        float2 f2 = reinterpret_cast<const float2*>(h0raw)[(size_t)wid * 32 + lane];
        hw32out[(size_t)wid * 32 + lane] = bfpack(f2.x * di, f2.y * di);
    }
}

// ------- FUSED: SpMM gather + BN + ReLU + next-layer GEMM (row-local) -------
// Phase A: 8 nodes/block (2 per wave), shfl-broadcast raw-w keys, accumulate
//   S = sum(w_e * h'[src]) + h'[n]   (h' rows are dinv-prescaled by producer)
//   out_ch = ReLU(BN(S * dinv[n] + b)) -> LDS hs[8][64]
// Phase B: Y[8,64] = hs @ W (LDS), epilogue * dinv[row], packed bf16 out.
// R6 lesson: do NOT add more phases (VGPR collapse to 32 serialized the MLP).

__global__ __launch_bounds__(256) void k_gather_gemm(
    const unsigned* __restrict__ hw32, const int* __restrict__ cur,
    const unsigned* __restrict__ epk, const float* __restrict__ dinv,
    const float* __restrict__ bb, const float* __restrict__ gg,
    const float* __restrict__ btp, const float* __restrict__ rmp,
    const float* __restrict__ rvp, const float* __restrict__ W,
    unsigned* __restrict__ out32) {
    __shared__ float Ws[64 * 64];
    __shared__ float hs[8][64];
    int tid = threadIdx.x;
    for (int idx = tid; idx < 64 * 64; idx += 256)   // issued early, waits at barrier
        Ws[idx] = W[idx];

    int lane = tid & 63;
    int l5 = lane & 31;
    int local = (tid >> 6) * 2 + (lane >> 5);        // 0..7
    int n = blockIdx.x * 8 + local;
    float di = dinv[n];
    unsigned us = hw32[(size_t)n * 32 + l5];
    float a0 = bflo(us), b0 = bfhi(us);              // self loop (h' prescaled)
    float a1 = 0.f, b1 = 0.f, a2 = 0.f, b2 = 0.f;
    float a3 = 0.f, b3 = 0.f, a4 = 0.f, b4 = 0.f;
    int cnt = min(cur[n], CAP);
    const unsigned* ce = epk + (size_t)n * CAP;
    const float q = 1.0f / WQ;
    unsigned klo = (l5 < cnt) ? ce[l5] : 0u;
    unsigned khi = 0u;
    if (cnt > 32) khi = (32 + l5 < cnt) ? ce[32 + l5] : 0u;
    int p = 0;
    for (; p + 8 <= cnt; p += 8) {
        unsigned base = (p < 32) ? klo : khi;
        int pb = p & 31;
        unsigned k0 = __shfl(base, pb + 0, 32);
        unsigned k1 = __shfl(base, pb + 1, 32);
        unsigned k2 = __shfl(base, pb + 2, 32);
        unsigned k3 = __shfl(base, pb + 3, 32);
        unsigned k4 = __shfl(base, pb + 4, 32);
        unsigned k5 = __shfl(base, pb + 5, 32);
        unsigned k6 = __shfl(base, pb + 6, 32);
        unsigned k7 = __shfl(base, pb + 7, 32);
        unsigned u0 = hw32[(size_t)(k0 >> 15) * 32 + l5];
        unsigned u1 = hw32[(size_t)(k1 >> 15) * 32 + l5];
        unsigned u2 = hw32[(size_t)(k2 >> 15) * 32 + l5];
        unsigned u3 = hw32[(size_t)(k3 >> 15) * 32 + l5];
        unsigned u4 = hw32[(size_t)(k4 >> 15) * 32 + l5];
        unsigned u5 = hw32[(size_t)(k5 >> 15) * 32 + l5];
        unsigned u6 = hw32[(size_t)(k6 >> 15) * 32 + l5];
        unsigned u7 = hw32[(size_t)(k7 >> 15) * 32 + l5];
        float c0 = (float)(k0 & 0x7fffu) * q, c1 = (float)(k1 & 0x7fffu) * q;
        float c2 = (float)(k2 & 0x7fffu) * q, c3 = (float)(k3 & 0x7fffu) * q;
        float c4 = (float)(k4 & 0x7fffu) * q, c5 = (float)(k5 & 0x7fffu) * q;
        float c6 = (float)(k6 & 0x7fffu) * q, c7 = (float)(k7 & 0x7fffu) * q;
        a0 += bflo(u0) * c0; b0 += bfhi(u0) * c0;
        a1 += bflo(u1) * c1; b1 += bfhi(u1) * c1;
        a2 += bflo(u2) * c2; b2 += bfhi(u2) * c2;
        a3 += bflo(u3) * c3; b3 += bfhi(u3) * c3;
        a4 += bflo(u4) * c4; b4 += bfhi(u4) * c4;
        a0 += bflo(u5) * c5; b0 += bfhi(u5) * c5;
        a1 += bflo(u6) * c6; b1 += bfhi(u6) * c6;
        a2 += bflo(u7) * c7; b2 += bfhi(u7) * c7;
    }
    for (; p + 4 <= cnt; p += 4) {
        unsigned base = (p < 32) ? klo : khi;
        int pb = p & 31;
        unsigned k0 = __shfl(base, pb + 0, 32);
        unsigned k1 = __shfl(base, pb + 1, 32);
        unsigned k2 = __shfl(base, pb + 2, 32);
        unsigned k3 = __shfl(base, pb + 3, 32);
        unsigned u0 = hw32[(size_t)(k0 >> 15) * 32 + l5];
        unsigned u1 = hw32[(size_t)(k1 >> 15) * 32 + l5];
        unsigned u2 = hw32[(size_t)(k2 >> 15) * 32 + l5];
        unsigned u3 = hw32[(size_t)(k3 >> 15) * 32 + l5];
        float c0 = (float)(k0 & 0x7fffu) * q, c1 = (float)(k1 & 0x7fffu) * q;
        float c2 = (float)(k2 & 0x7fffu) * q, c3 = (float)(k3 & 0x7fffu) * q;
        a0 += bflo(u0) * c0; b0 += bfhi(u0) * c0;
        a1 += bflo(u1) * c1; b1 += bfhi(u1) * c1;
        a2 += bflo(u2) * c2; b2 += bfhi(u2) * c2;
        a3 += bflo(u3) * c3; b3 += bfhi(u3) * c3;
    }
    for (; p < cnt; ++p) {
        unsigned base = (p < 32) ? klo : khi;
        unsigned k0 = __shfl(base, p & 31, 32);
        unsigned u0 = hw32[(size_t)(k0 >> 15) * 32 + l5];
        float c0 = (float)(k0 & 0x7fffu) * q;
        a0 += bflo(u0) * c0; b0 += bfhi(u0) * c0;
    }
    int cl = l5 * 2, ch = cl + 1;
    float alo = (((a0 + a1) + (a2 + a3)) + a4) * di + bb[cl];
    float ahi = (((b0 + b1) + (b2 + b3)) + b4) * di + bb[ch];
    float slo = gg[cl] * rsqrtf(rvp[cl] + BN_EPS);
    float shi = gg[ch] * rsqrtf(rvp[ch] + BN_EPS);
    hs[local][cl] = fmaxf((alo - rmp[cl]) * slo + btp[cl], 0.f);
    hs[local][ch] = fmaxf((ahi - rmp[ch]) * shi + btp[ch], 0.f);
    __syncthreads();

    // ---- Phase B: per-thread 2 adjacent output channels of one node ----
    int r = tid >> 5;            // 0..7 local node
    int pr = tid & 31;           // channel pair
    int c2 = pr * 2;
    float accl = 0.f, acch = 0.f;
#pragma unroll 8
    for (int k = 0; k < 64; ++k) {
        float h = hs[r][k];
        accl += h * Ws[k * 64 + c2];
        acch += h * Ws[k * 64 + c2 + 1];
    }
    int rn = blockIdx.x * 8 + r;
    float dib = dinv[rn];
    out32[(size_t)rn * 32 + pr] = bfpack(accl * dib, acch * dib);
}

// ------- Final-layer SpMM gather + BN (no following GEMM; feeds pool) -------

__global__ __launch_bounds__(256) void k_gather_bn(
    const unsigned* __restrict__ hw32, const int* __restrict__ cur,
    const unsigned* __restrict__ epk, const float* __restrict__ dinv,
    const float* __restrict__ bb, const float* __restrict__ gg,
    const float* __restrict__ btp, const float* __restrict__ rmp,
    const float* __restrict__ rvp, unsigned* __restrict__ ho32) {
    int wave = (blockIdx.x * 256 + threadIdx.x) >> 6;
    int lane = threadIdx.x & 63;
    int n = wave * 2 + (lane >> 5);       // node (2 per wave)
    int l5 = lane & 31;                   // uint index = channel pair
    if (n >= NN) return;
    float di = dinv[n];
    unsigned us = hw32[(size_t)n * 32 + l5];
    float a0 = bflo(us), b0 = bfhi(us);   // self loop (h' prescaled)
    float a1 = 0.f, b1 = 0.f, a2 = 0.f, b2 = 0.f;
    float a3 = 0.f, b3 = 0.f, a4 = 0.f, b4 = 0.f;
    int cnt = min(cur[n], CAP);
    const unsigned* ce = epk + (size_t)n * CAP;
    const float q = 1.0f / WQ;
    unsigned klo = (l5 < cnt) ? ce[l5] : 0u;
    unsigned khi = 0u;
    if (cnt > 32) khi = (32 + l5 < cnt) ? ce[32 + l5] : 0u;
    int p = 0;
    for (; p + 8 <= cnt; p += 8) {
        unsigned base = (p < 32) ? klo : khi;
        int pb = p & 31;
        unsigned k0 = __shfl(base, pb + 0, 32);
        unsigned k1 = __shfl(base, pb + 1, 32);
        unsigned k2 = __shfl(base, pb + 2, 32);
        unsigned k3 = __shfl(base, pb + 3, 32);
        unsigned k4 = __shfl(base, pb + 4, 32);
        unsigned k5 = __shfl(base, pb + 5, 32);
        unsigned k6 = __shfl(base, pb + 6, 32);
        unsigned k7 = __shfl(base, pb + 7, 32);
        unsigned u0 = hw32[(size_t)(k0 >> 15) * 32 + l5];
        unsigned u1 = hw32[(size_t)(k1 >> 15) * 32 + l5];
        unsigned u2 = hw32[(size_t)(k2 >> 15) * 32 + l5];
        unsigned u3 = hw32[(size_t)(k3 >> 15) * 32 + l5];
        unsigned u4 = hw32[(size_t)(k4 >> 15) * 32 + l5];
        unsigned u5 = hw32[(size_t)(k5 >> 15) * 32 + l5];
        unsigned u6 = hw32[(size_t)(k6 >> 15) * 32 + l5];
        unsigned u7 = hw32[(size_t)(k7 >> 15) * 32 + l5];
        float c0 = (float)(k0 & 0x7fffu) * q, c1 = (float)(k1 & 0x7fffu) * q;
        float c2 = (float)(k2 & 0x7fffu) * q, c3 = (float)(k3 & 0x7fffu) * q;
        float c4 = (float)(k4 & 0x7fffu) * q, c5 = (float)(k5 & 0x7fffu) * q;
        float c6 = (float)(k6 & 0x7fffu) * q, c7 = (float)(k7 & 0x7fffu) * q;
        a0 += bflo(u0) * c0; b0 += bfhi(u0) * c0;
        a1 += bflo(u1) * c1; b1 += bfhi(u1) * c1;
        a2 += bflo(u2) * c2; b2 += bfhi(u2) * c2;
        a3 += bflo(u3) * c3; b3 += bfhi(u3) * c3;
        a4 += bflo(u4) * c4; b4 += bfhi(u4) * c4;
        a0 += bflo(u5) * c5; b0 += bfhi(u5) * c5;
        a1 += bflo(u6) * c6; b1 += bfhi(u6) * c6;
        a2 += bflo(u7) * c7; b2 += bfhi(u7) * c7;
    }
    for (; p + 4 <= cnt; p += 4) {
        unsigned base = (p < 32) ? klo : khi;
        int pb = p & 31;
        unsigned k0 = __shfl(base, pb + 0, 32);
        unsigned k1 = __shfl(base, pb + 1, 32);
        unsigned k2 = __shfl(base, pb + 2, 32);
        unsigned k3 = __shfl(base, pb + 3, 32);
        unsigned u0 = hw32[(size_t)(k0 >> 15) * 32 + l5];
        unsigned u1 = hw32[(size_t)(k1 >> 15) * 32 + l5];
        unsigned u2 = hw32[(size_t)(k2 >> 15) * 32 + l5];
        unsigned u3 = hw32[(size_t)(k3 >> 15) * 32 + l5];
        float c0 = (float)(k0 & 0x7fffu) * q, c1 = (float)(k1 & 0x7fffu) * q;
        float c2 = (float)(k2 & 0x7fffu) * q, c3 = (float)(k3 & 0x7fffu) * q;
        a0 += bflo(u0) * c0; b0 += bfhi(u0) * c0;
        a1 += bflo(u1) * c1; b1 += bfhi(u1) * c1;
        a2 += bflo(u2) * c2; b2 += bfhi(u2) * c2;
        a3 += bflo(u3) * c3; b3 += bfhi(u3) * c3;
    }
    for (; p < cnt; ++p) {
        unsigned base = (p < 32) ? klo : khi;
        unsigned k0 = __shfl(base, p & 31, 32);
        unsigned u0 = hw32[(size_t)(k0 >> 15) * 32 + l5];
        float c0 = (float)(k0 & 0x7fffu) * q;
        a0 += bflo(u0) * c0; b0 += bfhi(u0) * c0;
    }
    int cl = l5 * 2, ch = cl + 1;
    float alo = (((a0 + a1) + (a2 + a3)) + a4) * di + bb[cl];
    float ahi = (((b0 + b1) + (b2 + b3)) + b4) * di + bb[ch];
    float slo = gg[cl] * rsqrtf(rvp[cl] + BN_EPS);
    float shi = gg[ch] * rsqrtf(rvp[ch] + BN_EPS);
    float olo = fmaxf((alo - rmp[cl]) * slo + btp[cl], 0.f);
    float ohi = fmaxf((ahi - rmp[ch]) * shi + btp[ch], 0.f);
    ho32[(size_t)n * 32 + l5] = bfpack(olo, ohi);
}

// ---------------- Pooling (batch sorted; 64 nodes/block) ----------------

__global__ __launch_bounds__(64) void k_pool(const bf16* __restrict__ h,
                                             const int* __restrict__ batch,
                                             float* __restrict__ s, float* __restrict__ cntf) {
    int c = threadIdx.x;
    int n0 = blockIdx.x * 64;
    if (n0 >= NN) return;
    int n1 = n0 + 64; if (n1 > NN) n1 = NN;
    float acc = 0.f, cnt = 0.f;
    int gcur = batch[n0];
    for (int i = n0; i < n1; ++i) {
        int gi = batch[i];
        if (gi != gcur) {
            atomicAdd(&s[gcur * 64 + c], acc);
            if (c == 0) atomicAdd(&cntf[gcur], cnt);
            acc = 0.f; cnt = 0.f; gcur = gi;
        }
        acc += __bfloat162float(h[(size_t)i * 64 + c]);
        cnt += 1.f;
    }
    atomicAdd(&s[gcur * 64 + c], acc);
    if (c == 0) atomicAdd(&cntf[gcur], cnt);
}

// ---------------- output: FLOAT32 ----------------

__global__ void k_out(const float* __restrict__ s, const float* __restrict__ cntf,
                      float* __restrict__ out) {
    int idx = blockIdx.x * 256 + threadIdx.x;
    if (idx >= GG * 128) return;
    int g = idx >> 7, c = idx & 127;
    float v;
    if (c < 64) v = s[g * 64 + c] / fmaxf(cntf[g], 1.f);
    else        v = s[g * 64 + (c - 64)];
    out[idx] = v;
}

// ---------------- launch ----------------

extern "C" void kernel_launch(void* const* d_in, const int* in_sizes, int n_in,
                              void* d_out, int out_size, void* d_ws, size_t ws_size,
                              hipStream_t stream) {
    const float* x   = (const float*)d_in[0];
    const int* ei    = (const int*)d_in[1];
    const float* ew  = (const float*)d_in[2];
    const int* batch = (const int*)d_in[3];
    const float *Wp[3], *bp[3], *gp[3], *btp[3], *rmp[3], *rvp[3];
    for (int l = 0; l < 3; ++l) {
        Wp[l]  = (const float*)d_in[4 + 6 * l + 0];
        bp[l]  = (const float*)d_in[4 + 6 * l + 1];
        gp[l]  = (const float*)d_in[4 + 6 * l + 2];
        btp[l] = (const float*)d_in[4 + 6 * l + 3];
        rmp[l] = (const float*)d_in[4 + 6 * l + 4];
        rvp[l] = (const float*)d_in[4 + 6 * l + 5];
    }

    size_t off = 0;
    auto carve = [&](size_t bytes) {
        void* r = (char*)d_ws + off;
        off += (bytes + 255) & ~(size_t)255;
        return r;
    };
    int*      cur    = (int*)     carve(NN * 4);
    float*    dinv   = (float*)   carve(NN * 4);
    unsigned* epk    = (unsigned*)carve((size_t)NN * CAP * 4);   // 25.6 MB
    float*    h0raw  = (float*)   carve((size_t)NN * 64 * 4);    // 25.6 MB (fp32 raw gemm0)
    bf16*     hw     = (bf16*)    carve((size_t)NN * 64 * 2);    // 12.8 MB
    bf16*     ha     = (bf16*)    carve((size_t)NN * 64 * 2);    // 12.8 MB
    float*    pool_s = (float*)   carve(GG * 64 * 4);
    float*    pool_c = (float*)   carve(GG * 4);

    hipMemsetAsync(cur, 0, NN * 4, stream);

    int nwblk  = (NN * 64 + 255) / 256;    // 25000 (wave per node)
    int gatblk = NN / 8;                   // 12500 (8 nodes/block)

    // scatter || layer-0 gemm in one dispatch
    k_scatter_gemm0<<<NGEMM + NSCAT, 256, 0, stream>>>(ei, ew, cur, epk, x, Wp[0], h0raw);
    // dinv + raw-row scale (h0raw*dinv -> hw bf16) + pool-accumulator zeroing
    k_dinv_scale<<<nwblk, 256, 0, stream>>>(cur, epk, dinv, h0raw, (unsigned*)hw,
                                            pool_s, pool_c);

    // gather L1 + BN(params0) + ReLU + GEMM(W1) + dinv prescale
    k_gather_gemm<<<gatblk, 256, 0, stream>>>((unsigned*)hw, cur, epk, dinv,
                                              bp[0], gp[0], btp[0], rmp[0], rvp[0],
                                              Wp[1], (unsigned*)ha);
    // gather L2 + BN(params1) + ReLU + GEMM(W2) + dinv prescale
    k_gather_gemm<<<gatblk, 256, 0, stream>>>((unsigned*)ha, cur, epk, dinv,
                                              bp[1], gp[1], btp[1], rmp[1], rvp[1],
                                              Wp[2], (unsigned*)hw);
    // gather L3 + BN(params2) + ReLU -> ha (feeds pool)
    k_gather_bn<<<gatblk, 256, 0, stream>>>((unsigned*)hw, cur, epk, dinv,
                                            bp[2], gp[2], btp[2], rmp[2], rvp[2], (unsigned*)ha);

    k_pool<<<NB_POOL, 64, 0, stream>>>(ha, batch, pool_s, pool_c);
    k_out<<<(GG * 128 + 255) / 256, 256, 0, stream>>>(pool_s, pool_c, (float*)d_out);
}

// Round 9
// 460.751 us; speedup vs baseline: 1.1021x; 1.1021x over previous
//
#include <hip/hip_runtime.h>
#include <hip/hip_bf16.h>

#define NN 100000
#define EE 1600000
#define GG 32
#define INC 100
#define HC 64
#define CAP 64        // ELL row capacity; P(Poisson(16) > 64) ~ 2e-18 per node
#define BN_EPS 1e-5f
#define NB_POOL 1563  // ceil(NN/64)
#define WQ 32767.0f   // 15-bit quantization scale
#define NSLICE 8      // XCD slices
#define SLICE_N 12500 // nodes per slice
#define EBLK 6250     // ceil(EE/256)

typedef __hip_bfloat16 bf16;

__device__ __forceinline__ float bflo(unsigned u) { return __uint_as_float(u << 16); }
__device__ __forceinline__ float bfhi(unsigned u) { return __uint_as_float(u & 0xffff0000u); }
__device__ __forceinline__ unsigned f2bf(float f) {
    unsigned x = __float_as_uint(f);
    return (x + 0x7fffu + ((x >> 16) & 1u)) >> 16;
}
__device__ __forceinline__ unsigned bfpack(float lo, float hi) {
    return f2bf(lo) | (f2bf(hi) << 16);
}

// ---------------- XCD-sliced ELL scatter ----------------
// Round-2 configuration (best measured): 1 edge/thread, NT streaming reads.
// R3: 8-way ILP regressed (TLP already hides latency; floor is TCC-side).
// R6: pool-fusion regressed (VGPR collapse). R8: merging gemm0 in regressed
// (LDS steals scatter occupancy). This kernel is at its measured floor.
// epk holds RAW |w| 15-bit fixed + src<<15 (k_norm deleted; dinv folded into
// GEMM epilogues + gather final multiply).

__global__ __launch_bounds__(256) void k_scatter_ell(const int* __restrict__ ei,
                                                     const float* __restrict__ ew,
                                                     int* __restrict__ cur,
                                                     unsigned* __restrict__ epk) {
    unsigned b = blockIdx.x;
    int slice = b & (NSLICE - 1);
    int e = (int)(b >> 3) * 256 + threadIdx.x;
    if (e >= EE) return;
    int d = __builtin_nontemporal_load(&ei[EE + e]);
    int lo = slice * SLICE_N;
    if (d < lo || d >= lo + SLICE_N) return;
    int s = __builtin_nontemporal_load(&ei[e]);
    float w = __builtin_nontemporal_load(&ew[e]);
    int qw = (int)(fabsf(w) * WQ + 0.5f);
    if (qw > 32767) qw = 32767;
    int slot = atomicAdd(&cur[d], 1);
    if (slot < CAP)
        epk[(size_t)d * CAP + slot] = ((unsigned)s << 15) | (unsigned)qw;
}

// wave per node: lane-sum of dequantized |w| -> dinv (no atomics).
// Block 0 also zeroes the pooling accumulators (replaces 2 hipMemsetAsync
// dispatches; stream ordering guarantees it completes before k_pool).

__global__ __launch_bounds__(256) void k_dinv_ell(const int* __restrict__ cur,
                                                  const unsigned* __restrict__ epk,
                                                  float* __restrict__ dinv,
                                                  float* __restrict__ pool_s,
                                                  float* __restrict__ pool_c) {
    if (blockIdx.x == 0) {
        for (int i = threadIdx.x; i < GG * 64 + GG; i += 256) {
            if (i < GG * 64) pool_s[i] = 0.f;
            else             pool_c[i - GG * 64] = 0.f;
        }
    }
    int wid = (blockIdx.x * 256 + threadIdx.x) >> 6;
    int lane = threadIdx.x & 63;
    if (wid >= NN) return;
    int cnt = min(cur[wid], CAP);
    float v = 0.f;
    if (lane < cnt)
        v = (float)(epk[(size_t)wid * CAP + lane] & 0x7fffu) * (1.0f / WQ);
    for (int o = 32; o > 0; o >>= 1) v += __shfl_down(v, o);
    if (lane == 0) dinv[wid] = rsqrtf(v + 1.0f);   // +1 = self-loop weight
}

// ---------------- GEMM: Y[N,64] = (X[N,DIN] @ W[DIN,64]) * dinv[row] ----------------

__device__ __forceinline__ float ldf(const float* p, size_t i) { return p[i]; }
__device__ __forceinline__ float ldf(const bf16* p, size_t i) { return __bfloat162float(p[i]); }

template <int DIN, typename Tin>
__global__ __launch_bounds__(256) void k_gemm(const Tin* __restrict__ X,
                                              const float* __restrict__ W,
                                              const float* __restrict__ dinv,
                                              bf16* __restrict__ Y) {
    __shared__ float Ws[DIN * 64];
    __shared__ float Xs[32 * DIN];
    int row0 = blockIdx.x * 32;
    for (int idx = threadIdx.x; idx < DIN * 64; idx += 256)
        Ws[idx] = W[idx];
    for (int idx = threadIdx.x; idx < 32 * DIN; idx += 256) {
        int r = idx / DIN, k = idx - r * DIN;
        Xs[idx] = ldf(X, (size_t)(row0 + r) * DIN + k);
    }
    __syncthreads();
    int c = threadIdx.x & 63;
    int r0 = threadIdx.x >> 6;   // 0..3
    float acc[8];
#pragma unroll
    for (int j = 0; j < 8; j++) acc[j] = 0.f;
    for (int k = 0; k < DIN; k++) {
        float wv = Ws[k * 64 + c];
#pragma unroll
        for (int j = 0; j < 8; j++)
            acc[j] += Xs[(r0 + j * 4) * DIN + k] * wv;
    }
#pragma unroll
    for (int j = 0; j < 8; j++) {
        int row = row0 + r0 + j * 4;
        Y[(size_t)row * 64 + c] = __float2bfloat16(acc[j] * dinv[row]);
    }
}

// ------- FUSED: SpMM gather + BN + ReLU + next-layer GEMM (row-local) -------
// Phase A: 8 nodes/block (2 per wave), shfl-broadcast raw-w keys, accumulate
//   S = sum(w_e * h'[src]) + h'[n]   (h' rows are dinv-prescaled by producer)
//   out_ch = ReLU(BN(S * dinv[n] + b)) -> LDS hs[8][64]
// Phase B: Y[8,64] = hs @ W (LDS), epilogue * dinv[row], packed bf16 out.
// R6 lesson: do NOT add more phases (VGPR collapse to 32 serialized the MLP).

__global__ __launch_bounds__(256) void k_gather_gemm(
    const unsigned* __restrict__ hw32, const int* __restrict__ cur,
    const unsigned* __restrict__ epk, const float* __restrict__ dinv,
    const float* __restrict__ bb, const float* __restrict__ gg,
    const float* __restrict__ btp, const float* __restrict__ rmp,
    const float* __restrict__ rvp, const float* __restrict__ W,
    unsigned* __restrict__ out32) {
    __shared__ float Ws[64 * 64];
    __shared__ float hs[8][64];
    int tid = threadIdx.x;
    for (int idx = tid; idx < 64 * 64; idx += 256)   // issued early, waits at barrier
        Ws[idx] = W[idx];

    int lane = tid & 63;
    int l5 = lane & 31;
    int local = (tid >> 6) * 2 + (lane >> 5);        // 0..7
    int n = blockIdx.x * 8 + local;
    float di = dinv[n];
    unsigned us = hw32[(size_t)n * 32 + l5];
    float a0 = bflo(us), b0 = bfhi(us);              // self loop (h' prescaled)
    float a1 = 0.f, b1 = 0.f, a2 = 0.f, b2 = 0.f;
    float a3 = 0.f, b3 = 0.f, a4 = 0.f, b4 = 0.f;
    int cnt = min(cur[n], CAP);
    const unsigned* ce = epk + (size_t)n * CAP;
    const float q = 1.0f / WQ;
    unsigned klo = (l5 < cnt) ? ce[l5] : 0u;
    unsigned khi = 0u;
    if (cnt > 32) khi = (32 + l5 < cnt) ? ce[32 + l5] : 0u;
    int p = 0;
    for (; p + 8 <= cnt; p += 8) {
        unsigned base = (p < 32) ? klo : khi;
        int pb = p & 31;
        unsigned k0 = __shfl(base, pb + 0, 32);
        unsigned k1 = __shfl(base, pb + 1, 32);
        unsigned k2 = __shfl(base, pb + 2, 32);
        unsigned k3 = __shfl(base, pb + 3, 32);
        unsigned k4 = __shfl(base, pb + 4, 32);
        unsigned k5 = __shfl(base, pb + 5, 32);
        unsigned k6 = __shfl(base, pb + 6, 32);
        unsigned k7 = __shfl(base, pb + 7, 32);
        unsigned u0 = hw32[(size_t)(k0 >> 15) * 32 + l5];
        unsigned u1 = hw32[(size_t)(k1 >> 15) * 32 + l5];
        unsigned u2 = hw32[(size_t)(k2 >> 15) * 32 + l5];
        unsigned u3 = hw32[(size_t)(k3 >> 15) * 32 + l5];
        unsigned u4 = hw32[(size_t)(k4 >> 15) * 32 + l5];
        unsigned u5 = hw32[(size_t)(k5 >> 15) * 32 + l5];
        unsigned u6 = hw32[(size_t)(k6 >> 15) * 32 + l5];
        unsigned u7 = hw32[(size_t)(k7 >> 15) * 32 + l5];
        float c0 = (float)(k0 & 0x7fffu) * q, c1 = (float)(k1 & 0x7fffu) * q;
        float c2 = (float)(k2 & 0x7fffu) * q, c3 = (float)(k3 & 0x7fffu) * q;
        float c4 = (float)(k4 & 0x7fffu) * q, c5 = (float)(k5 & 0x7fffu) * q;
        float c6 = (float)(k6 & 0x7fffu) * q, c7 = (float)(k7 & 0x7fffu) * q;
        a0 += bflo(u0) * c0; b0 += bfhi(u0) * c0;
        a1 += bflo(u1) * c1; b1 += bfhi(u1) * c1;
        a2 += bflo(u2) * c2; b2 += bfhi(u2) * c2;
        a3 += bflo(u3) * c3; b3 += bfhi(u3) * c3;
        a4 += bflo(u4) * c4; b4 += bfhi(u4) * c4;
        a0 += bflo(u5) * c5; b0 += bfhi(u5) * c5;
        a1 += bflo(u6) * c6; b1 += bfhi(u6) * c6;
        a2 += bflo(u7) * c7; b2 += bfhi(u7) * c7;
    }
    for (; p + 4 <= cnt; p += 4) {
        unsigned base = (p < 32) ? klo : khi;
        int pb = p & 31;
        unsigned k0 = __shfl(base, pb + 0, 32);
        unsigned k1 = __shfl(base, pb + 1, 32);
        unsigned k2 = __shfl(base, pb + 2, 32);
        unsigned k3 = __shfl(base, pb + 3, 32);
        unsigned u0 = hw32[(size_t)(k0 >> 15) * 32 + l5];
        unsigned u1 = hw32[(size_t)(k1 >> 15) * 32 + l5];
        unsigned u2 = hw32[(size_t)(k2 >> 15) * 32 + l5];
        unsigned u3 = hw32[(size_t)(k3 >> 15) * 32 + l5];
        float c0 = (float)(k0 & 0x7fffu) * q, c1 = (float)(k1 & 0x7fffu) * q;
        float c2 = (float)(k2 & 0x7fffu) * q, c3 = (float)(k3 & 0x7fffu) * q;
        a0 += bflo(u0) * c0; b0 += bfhi(u0) * c0;
        a1 += bflo(u1) * c1; b1 += bfhi(u1) * c1;
        a2 += bflo(u2) * c2; b2 += bfhi(u2) * c2;
        a3 += bflo(u3) * c3; b3 += bfhi(u3) * c3;
    }
    for (; p < cnt; ++p) {
        unsigned base = (p < 32) ? klo : khi;
        unsigned k0 = __shfl(base, p & 31, 32);
        unsigned u0 = hw32[(size_t)(k0 >> 15) * 32 + l5];
        float c0 = (float)(k0 & 0x7fffu) * q;
        a0 += bflo(u0) * c0; b0 += bfhi(u0) * c0;
    }
    int cl = l5 * 2, ch = cl + 1;
    float alo = (((a0 + a1) + (a2 + a3)) + a4) * di + bb[cl];
    float ahi = (((b0 + b1) + (b2 + b3)) + b4) * di + bb[ch];
    float slo = gg[cl] * rsqrtf(rvp[cl] + BN_EPS);
    float shi = gg[ch] * rsqrtf(rvp[ch] + BN_EPS);
    hs[local][cl] = fmaxf((alo - rmp[cl]) * slo + btp[cl], 0.f);
    hs[local][ch] = fmaxf((ahi - rmp[ch]) * shi + btp[ch], 0.f);
    __syncthreads();

    // ---- Phase B: per-thread 2 adjacent output channels of one node ----
    int r = tid >> 5;            // 0..7 local node
    int pr = tid & 31;           // channel pair
    int c2 = pr * 2;
    float accl = 0.f, acch = 0.f;
#pragma unroll 8
    for (int k = 0; k < 64; ++k) {
        float h = hs[r][k];
        accl += h * Ws[k * 64 + c2];
        acch += h * Ws[k * 64 + c2 + 1];
    }
    int rn = blockIdx.x * 8 + r;
    float dib = dinv[rn];
    out32[(size_t)rn * 32 + pr] = bfpack(accl * dib, acch * dib);
}

// ------- Final-layer SpMM gather + BN (no following GEMM; feeds pool) -------

__global__ __launch_bounds__(256) void k_gather_bn(
    const unsigned* __restrict__ hw32, const int* __restrict__ cur,
    const unsigned* __restrict__ epk, const float* __restrict__ dinv,
    const float* __restrict__ bb, const float* __restrict__ gg,
    const float* __restrict__ btp, const float* __restrict__ rmp,
    const float* __restrict__ rvp, unsigned* __restrict__ ho32) {
    int wave = (blockIdx.x * 256 + threadIdx.x) >> 6;
    int lane = threadIdx.x & 63;
    int n = wave * 2 + (lane >> 5);       // node (2 per wave)
    int l5 = lane & 31;                   // uint index = channel pair
    if (n >= NN) return;
    float di = dinv[n];
    unsigned us = hw32[(size_t)n * 32 + l5];
    float a0 = bflo(us), b0 = bfhi(us);   // self loop (h' prescaled)
    float a1 = 0.f, b1 = 0.f, a2 = 0.f, b2 = 0.f;
    float a3 = 0.f, b3 = 0.f, a4 = 0.f, b4 = 0.f;
    int cnt = min(cur[n], CAP);
    const unsigned* ce = epk + (size_t)n * CAP;
    const float q = 1.0f / WQ;
    unsigned klo = (l5 < cnt) ? ce[l5] : 0u;
    unsigned khi = 0u;
    if (cnt > 32) khi = (32 + l5 < cnt) ? ce[32 + l5] : 0u;
    int p = 0;
    for (; p + 8 <= cnt; p += 8) {
        unsigned base = (p < 32) ? klo : khi;
        int pb = p & 31;
        unsigned k0 = __shfl(base, pb + 0, 32);
        unsigned k1 = __shfl(base, pb + 1, 32);
        unsigned k2 = __shfl(base, pb + 2, 32);
        unsigned k3 = __shfl(base, pb + 3, 32);
        unsigned k4 = __shfl(base, pb + 4, 32);
        unsigned k5 = __shfl(base, pb + 5, 32);
        unsigned k6 = __shfl(base, pb + 6, 32);
        unsigned k7 = __shfl(base, pb + 7, 32);
        unsigned u0 = hw32[(size_t)(k0 >> 15) * 32 + l5];
        unsigned u1 = hw32[(size_t)(k1 >> 15) * 32 + l5];
        unsigned u2 = hw32[(size_t)(k2 >> 15) * 32 + l5];
        unsigned u3 = hw32[(size_t)(k3 >> 15) * 32 + l5];
        unsigned u4 = hw32[(size_t)(k4 >> 15) * 32 + l5];
        unsigned u5 = hw32[(size_t)(k5 >> 15) * 32 + l5];
        unsigned u6 = hw32[(size_t)(k6 >> 15) * 32 + l5];
        unsigned u7 = hw32[(size_t)(k7 >> 15) * 32 + l5];
        float c0 = (float)(k0 & 0x7fffu) * q, c1 = (float)(k1 & 0x7fffu) * q;
        float c2 = (float)(k2 & 0x7fffu) * q, c3 = (float)(k3 & 0x7fffu) * q;
        float c4 = (float)(k4 & 0x7fffu) * q, c5 = (float)(k5 & 0x7fffu) * q;
        float c6 = (float)(k6 & 0x7fffu) * q, c7 = (float)(k7 & 0x7fffu) * q;
        a0 += bflo(u0) * c0; b0 += bfhi(u0) * c0;
        a1 += bflo(u1) * c1; b1 += bfhi(u1) * c1;
        a2 += bflo(u2) * c2; b2 += bfhi(u2) * c2;
        a3 += bflo(u3) * c3; b3 += bfhi(u3) * c3;
        a4 += bflo(u4) * c4; b4 += bfhi(u4) * c4;
        a0 += bflo(u5) * c5; b0 += bfhi(u5) * c5;
        a1 += bflo(u6) * c6; b1 += bfhi(u6) * c6;
        a2 += bflo(u7) * c7; b2 += bfhi(u7) * c7;
    }
    for (; p + 4 <= cnt; p += 4) {
        unsigned base = (p < 32) ? klo : khi;
        int pb = p & 31;
        unsigned k0 = __shfl(base, pb + 0, 32);
        unsigned k1 = __shfl(base, pb + 1, 32);
        unsigned k2 = __shfl(base, pb + 2, 32);
        unsigned k3 = __shfl(base, pb + 3, 32);
        unsigned u0 = hw32[(size_t)(k0 >> 15) * 32 + l5];
        unsigned u1 = hw32[(size_t)(k1 >> 15) * 32 + l5];
        unsigned u2 = hw32[(size_t)(k2 >> 15) * 32 + l5];
        unsigned u3 = hw32[(size_t)(k3 >> 15) * 32 + l5];
        float c0 = (float)(k0 & 0x7fffu) * q, c1 = (float)(k1 & 0x7fffu) * q;
        float c2 = (float)(k2 & 0x7fffu) * q, c3 = (float)(k3 & 0x7fffu) * q;
        a0 += bflo(u0) * c0; b0 += bfhi(u0) * c0;
        a1 += bflo(u1) * c1; b1 += bfhi(u1) * c1;
        a2 += bflo(u2) * c2; b2 += bfhi(u2) * c2;
        a3 += bflo(u3) * c3; b3 += bfhi(u3) * c3;
    }
    for (; p < cnt; ++p) {
        unsigned base = (p < 32) ? klo : khi;
        unsigned k0 = __shfl(base, p & 31, 32);
        unsigned u0 = hw32[(size_t)(k0 >> 15) * 32 + l5];
        float c0 = (float)(k0 & 0x7fffu) * q;
        a0 += bflo(u0) * c0; b0 += bfhi(u0) * c0;
    }
    int cl = l5 * 2, ch = cl + 1;
    float alo = (((a0 + a1) + (a2 + a3)) + a4) * di + bb[cl];
    float ahi = (((b0 + b1) + (b2 + b3)) + b4) * di + bb[ch];
    float slo = gg[cl] * rsqrtf(rvp[cl] + BN_EPS);
    float shi = gg[ch] * rsqrtf(rvp[ch] + BN_EPS);
    float olo = fmaxf((alo - rmp[cl]) * slo + btp[cl], 0.f);
    float ohi = fmaxf((ahi - rmp[ch]) * shi + btp[ch], 0.f);
    ho32[(size_t)n * 32 + l5] = bfpack(olo, ohi);
}

// ---------------- Pooling (batch sorted; 64 nodes/block) ----------------

__global__ __launch_bounds__(64) void k_pool(const bf16* __restrict__ h,
                                             const int* __restrict__ batch,
                                             float* __restrict__ s, float* __restrict__ cntf) {
    int c = threadIdx.x;
    int n0 = blockIdx.x * 64;
    if (n0 >= NN) return;
    int n1 = n0 + 64; if (n1 > NN) n1 = NN;
    float acc = 0.f, cnt = 0.f;
    int gcur = batch[n0];
    for (int i = n0; i < n1; ++i) {
        int gi = batch[i];
        if (gi != gcur) {
            atomicAdd(&s[gcur * 64 + c], acc);
            if (c == 0) atomicAdd(&cntf[gcur], cnt);
            acc = 0.f; cnt = 0.f; gcur = gi;
        }
        acc += __bfloat162float(h[(size_t)i * 64 + c]);
        cnt += 1.f;
    }
    atomicAdd(&s[gcur * 64 + c], acc);
    if (c == 0) atomicAdd(&cntf[gcur], cnt);
}

// ---------------- output: FLOAT32 ----------------

__global__ void k_out(const float* __restrict__ s, const float* __restrict__ cntf,
                      float* __restrict__ out) {
    int idx = blockIdx.x * 256 + threadIdx.x;
    if (idx >= GG * 128) return;
    int g = idx >> 7, c = idx & 127;
    float v;
    if (c < 64) v = s[g * 64 + c] / fmaxf(cntf[g], 1.f);
    else        v = s[g * 64 + (c - 64)];
    out[idx] = v;
}

// ---------------- launch ----------------

extern "C" void kernel_launch(void* const* d_in, const int* in_sizes, int n_in,
                              void* d_out, int out_size, void* d_ws, size_t ws_size,
                              hipStream_t stream) {
    const float* x   = (const float*)d_in[0];
    const int* ei    = (const int*)d_in[1];
    const float* ew  = (const float*)d_in[2];
    const int* batch = (const int*)d_in[3];
    const float *Wp[3], *bp[3], *gp[3], *btp[3], *rmp[3], *rvp[3];
    for (int l = 0; l < 3; ++l) {
        Wp[l]  = (const float*)d_in[4 + 6 * l + 0];
        bp[l]  = (const float*)d_in[4 + 6 * l + 1];
        gp[l]  = (const float*)d_in[4 + 6 * l + 2];
        btp[l] = (const float*)d_in[4 + 6 * l + 3];
        rmp[l] = (const float*)d_in[4 + 6 * l + 4];
        rvp[l] = (const float*)d_in[4 + 6 * l + 5];
    }

    size_t off = 0;
    auto carve = [&](size_t bytes) {
        void* r = (char*)d_ws + off;
        off += (bytes + 255) & ~(size_t)255;
        return r;
    };
    int*      cur    = (int*)     carve(NN * 4);
    float*    dinv   = (float*)   carve(NN * 4);
    unsigned* epk    = (unsigned*)carve((size_t)NN * CAP * 4);   // 25.6 MB
    bf16*     hw     = (bf16*)    carve((size_t)NN * 64 * 2);    // 12.8 MB
    bf16*     ha     = (bf16*)    carve((size_t)NN * 64 * 2);    // 12.8 MB
    float*    pool_s = (float*)   carve(GG * 64 * 4);
    float*    pool_c = (float*)   carve(GG * 4);

    hipMemsetAsync(cur, 0, NN * 4, stream);

    int nwblk  = (NN * 64 + 255) / 256;    // 25000 (wave per node)
    int gatblk = NN / 8;                   // 12500 (8 nodes/block)
    int gemm_grid = NN / 32;               // 3125

    k_scatter_ell<<<EBLK * NSLICE, 256, 0, stream>>>(ei, ew, cur, epk);
    k_dinv_ell<<<nwblk, 256, 0, stream>>>(cur, epk, dinv, pool_s, pool_c);

    // layer 0 GEMM (output rows prescaled by dinv)
    k_gemm<INC, float><<<gemm_grid, 256, 0, stream>>>(x, Wp[0], dinv, hw);
    // gather L1 + BN(params0) + ReLU + GEMM(W1) + dinv prescale
    k_gather_gemm<<<gatblk, 256, 0, stream>>>((unsigned*)hw, cur, epk, dinv,
                                              bp[0], gp[0], btp[0], rmp[0], rvp[0],
                                              Wp[1], (unsigned*)ha);
    // gather L2 + BN(params1) + ReLU + GEMM(W2) + dinv prescale
    k_gather_gemm<<<gatblk, 256, 0, stream>>>((unsigned*)ha, cur, epk, dinv,
                                              bp[1], gp[1], btp[1], rmp[1], rvp[1],
                                              Wp[2], (unsigned*)hw);
    // gather L3 + BN(params2) + ReLU -> ha (feeds pool)
    k_gather_bn<<<gatblk, 256, 0, stream>>>((unsigned*)hw, cur, epk, dinv,
                                            bp[2], gp[2], btp[2], rmp[2], rvp[2], (unsigned*)ha);

    k_pool<<<NB_POOL, 64, 0, stream>>>(ha, batch, pool_s, pool_c);
    k_out<<<(GG * 128 + 255) / 256, 256, 0, stream>>>(pool_s, pool_c, (float*)d_out);
}